// Round 15
// baseline (91.371 us; speedup 1.0000x reference)
//
#include <hip/hip_runtime.h>

#define NPIX 409600   // 640*640
#define NB 8          // batch

// ---------------- workspace layout (4-byte words, per batch) ----------------
constexpr int OFF_H0   = 0;     // 2048 u32  level-0 hist (key bits 31..21)
constexpr int OFF_H1   = 2048;  // 2048 u32  level-1 hist (bits 20..10)
constexpr int OFF_H2   = 4096;  // 1024 u32  level-2 hist (bits 9..0)
constexpr int OFF_KC   = 5120;  // 8 u32   kernel-mask counts
constexpr int OFF_TC   = 5128;  // 8 u32   text-mask counts
constexpr int OFF_KS   = 5136;  // 32 f32  kernel-mask sim sums (inst*4+c)
constexpr int OFF_AGG  = 5168;  // 8 f32   per-instance sum log1p(D)
constexpr int OFF_CPOS = 5176;  // u32
constexpr int OFF_CPOSM= 5177;  // u32
constexpr int OFF_KN   = 5178;  // u32  list-A count (all negs)
constexpr int OFF_KNF  = 5179;  // u32  list-B count (flagged negs)
constexpr int OFF_FALL = 5180;  // u32
constexpr int OFF_NV   = 5181;  // u32
constexpr int OFF_VM   = 5182;  // u32
constexpr int OFF_LDIS = 5183;  // f32
constexpr int OFF_BTN  = 5184;  // f32  bt_neg (threshold-dependent dice part)
constexpr int OFF_PFX0 = 5185;  // u32
constexpr int OFF_K1   = 5186;  // u32
constexpr int OFF_PFX22= 5187;  // u32
constexpr int OFF_K2   = 5188;  // u32
constexpr int OFF_DICE = 5190;  // 9 f32: at,btp,ct, atf,btf,ctf, ak,bk,ck
constexpr int PER_BATCH= 5248;
constexpr int KEYS_BASE= NB * PER_BATCH;
constexpr int HDR_WORDS= NB * PER_BATCH;
// per-batch key region (NPIX words): list A grows up from 0,
// list B (flagged) grows down from NPIX-1.

__device__ __forceinline__ unsigned mapf(float s) {
  unsigned b = __float_as_uint(s);
  return (b & 0x80000000u) ? ~b : (b | 0x80000000u);
}
__device__ __forceinline__ float unmapf(unsigned u) {
  return __uint_as_float((u & 0x80000000u) ? (u & 0x7FFFFFFFu) : ~u);
}
__device__ __forceinline__ float sigf(float x) {
  return __fdividef(1.f, 1.f + __expf(-x));
}
__device__ __forceinline__ float wredf(float v) {
#pragma unroll
  for (int m = 32; m >= 1; m >>= 1) v += __shfl_xor(v, m, 64);
  return v;
}
__device__ __forceinline__ unsigned wredu(unsigned v) {
#pragma unroll
  for (int m = 32; m >= 1; m >>= 1) v += (unsigned)__shfl_xor((int)v, m, 64);
  return v;
}

// ---- kZ ---------------------------------------------------------------------
__global__ __launch_bounds__(256) void kZ(unsigned* __restrict__ ws) {
  int i = blockIdx.x * 256 + threadIdx.x;
  if (i < HDR_WORDS) ws[i] = 0u;
}

// ---- kXS: one launch, three block roles. Union LDS 9.6 KB. -----------------
// role X  (blocks 0..199):  hist0 + counters + TC (reg) + thr-indep dice
//                           + dual register-resident key compaction.
// role S01 (200..327): sim c0/c1 + KC — ALL register accumulators (21 regs,
//                      no LDS RMW chain; R14 lesson: LDS RMW was the stall).
// role S23 (328..455): sim c2/c3, register accumulators.
__global__ __launch_bounds__(256) void kXS(const float* __restrict__ out_,
                                           const int* __restrict__ lab_,
                                           const float* __restrict__ tm_,
                                           unsigned* __restrict__ ws) {
  const int b = blockIdx.y;
  unsigned* wsb = ws + (size_t)b * PER_BATCH;
  float* wsbf = (float*)wsb;
  __shared__ __align__(16) unsigned shm[2384];   // union of role layouts
  const int tid = threadIdx.x, lane = tid & 63, w = tid >> 6;

  if (blockIdx.x < 200) {
    // ========================= role X =========================
    const int bx = blockIdx.x;
    unsigned* sh_h   = shm;                   // 2048
    unsigned* shScan = shm + 2048;            // 256
    unsigned* shTC   = shm + 2304;            // 28
    float*    shRed  = (float*)(shm + 2332);  // 36
    unsigned* shC    = shm + 2368;            // 8
    unsigned* shBase = shm + 2376;            // 2
    for (int i = tid; i < 2048; i += 256) sh_h[i] = 0u;
    __syncthreads();

    const float4* tx = (const float4*)(out_ + (size_t)b * 6 * NPIX);
    const float4* kr = (const float4*)(out_ + (size_t)b * 6 * NPIX + (size_t)NPIX);
    const int4* gt = (const int4*)(lab_ + (size_t)b * 2 * NPIX);
    const int4* gk = (const int4*)(lab_ + (size_t)b * 2 * NPIX + NPIX);
    const float4* tmv = (const float4*)(tm_ + (size_t)b * NPIX);

    unsigned cpos = 0, cposm = 0, vmask = 0, fmask = 0;
    unsigned tcq[7];
#pragma unroll
    for (int k = 0; k < 7; ++k) tcq[k] = 0u;
    unsigned kreg[8];
    float at = 0.f, btp = 0.f, ct = 0.f, atf = 0.f, btf = 0.f, ctf = 0.f;
    float ak = 0.f, bk = 0.f, ck = 0.f;

#pragma unroll
    for (int it = 0; it < 2; ++it) {
      const int i = it * 51200 + bx * 256 + tid;
      float4 t4 = tx[i]; float4 q4 = kr[i]; int4 g4 = gt[i]; int4 k4 = gk[i]; float4 m4 = tmv[i];
#pragma unroll
      for (int j = 0; j < 4; ++j) {
        float tv = ((const float*)&t4)[j];
        float kv = ((const float*)&q4)[j];
        int gtv = ((const int*)&g4)[j];
        int gkv = ((const int*)&k4)[j];
        float mv = ((const float*)&m4)[j];
        bool pos = gtv > 0;
        bool mh = mv > 0.5f;
        cpos += pos;
        cposm += (pos && !mh);
        unsigned key = mapf(tv);
        kreg[it * 4 + j] = key;
        float sig = sigf(tv);
        if (!pos) {
          vmask |= 1u << (it * 4 + j);
          if (mh) fmask |= 1u << (it * 4 + j);
          atomicAdd(&sh_h[key >> 21], 1u);
        } else if (mh) {
          at += sig; btp += sig * sig; ct += 1.f;
        }
#pragma unroll
        for (int k = 0; k < 7; ++k)
          tcq[k] += (gtv == k + 1);         // per-thread, no ballot/SALU
        float sm = sig * mv;           // fallback dice (sel = tm float)
        btf += sm * sm;
        if (pos) { atf += sm * mv; ctf += mv * mv; }
        if ((tv > 0.f) && mh) {        // kernel dice
          float sk = sigf(kv);
          bk += sk * sk;
          if (gkv > 0) { ak += sk; ck += 1.f; }
        }
      }
    }

    unsigned r = wredu(cpos), r2 = wredu(cposm);
    if (lane == 0) { shC[w * 2] = r; shC[w * 2 + 1] = r2; }
#pragma unroll
    for (int k = 0; k < 7; ++k) {
      unsigned rt = wredu(tcq[k]);
      if (lane == 0) shTC[w * 7 + k] = rt;
    }
    float v9[9] = {at, btp, ct, atf, btf, ctf, ak, bk, ck};
#pragma unroll
    for (int q = 0; q < 9; ++q) {
      float f = wredf(v9[q]);
      if (lane == 0) shRed[w * 9 + q] = f;
    }

    unsigned cnt = (unsigned)__popc(vmask), cntF = (unsigned)__popc(fmask);
    shScan[tid] = cnt | (cntF << 16);
    __syncthreads();
#pragma unroll
    for (int off = 1; off < 256; off <<= 1) {
      unsigned vv = (tid >= off) ? shScan[tid - off] : 0u;
      __syncthreads();
      shScan[tid] += vv;
      __syncthreads();
    }
    if (tid == 0) {
      unsigned tot = shScan[255];
      shBase[0] = atomicAdd(&wsb[OFF_KN], tot & 0xFFFFu);
      shBase[1] = atomicAdd(&wsb[OFF_KNF], tot >> 16);
    }
    for (int i = tid; i < 2048; i += 256) {
      unsigned h = sh_h[i]; if (h) atomicAdd(&wsb[OFF_H0 + i], h);
    }
    if (tid < 7) {
      unsigned s = shTC[tid] + shTC[7 + tid] + shTC[14 + tid] + shTC[21 + tid];
      if (s) atomicAdd(&wsb[OFF_TC + 1 + tid], s);
    } else if (tid >= 16 && tid < 25) {
      int q = tid - 16;
      float s = shRed[q] + shRed[9 + q] + shRed[18 + q] + shRed[27 + q];
      atomicAdd(&wsbf[OFF_DICE + q], s);
    } else if (tid == 30) {
      atomicAdd(&wsb[OFF_CPOS], shC[0] + shC[2] + shC[4] + shC[6]);
    } else if (tid == 31) {
      atomicAdd(&wsb[OFF_CPOSM], shC[1] + shC[3] + shC[5] + shC[7]);
    }
    __syncthreads();
    unsigned gA = shBase[0] + (shScan[tid] & 0xFFFFu) - cnt;
    unsigned gF = shBase[1] + (shScan[tid] >> 16) - cntF;
    unsigned* keys = ws + KEYS_BASE + (size_t)b * NPIX;
#pragma unroll
    for (int s = 0; s < 8; ++s)
      if (vmask & (1u << s)) { keys[gA] = kreg[s]; ++gA; }
#pragma unroll
    for (int s = 0; s < 8; ++s)
      if (fmask & (1u << s)) { keys[NPIX - 1 - gF] = kreg[s]; ++gF; }
  } else {
    // ==================== roles S01 / S23 (register accumulators) ===========
    const bool lo = blockIdx.x < 328;    // channels {0,1} : {2,3}
    const int bx = lo ? (blockIdx.x - 200) : (blockIdx.x - 328);
    float* shSred = (float*)shm;         // [4 waves][14]
    unsigned* shScnt = shm + 64;         // [4 waves][7]

    const float4* sa = (const float4*)(out_ + (size_t)b * 6 * NPIX + (size_t)(lo ? 2 : 4) * NPIX);
    const float4* sb = (const float4*)(out_ + (size_t)b * 6 * NPIX + (size_t)(lo ? 3 : 5) * NPIX);
    const int4* gkk = (const int4*)(lab_ + (size_t)b * 2 * NPIX + NPIX);

    float ka[7], kb2[7];
    unsigned kcq[7];
#pragma unroll
    for (int k = 0; k < 7; ++k) { ka[k] = 0.f; kb2[k] = 0.f; kcq[k] = 0u; }

    const int nv = NPIX / 4;
    for (int i = bx * 256 + tid; i < nv; i += 128 * 256) {
      int4 k4 = gkk[i];
      float4 a0 = sa[i], a1 = sb[i];
#pragma unroll
      for (int j = 0; j < 4; ++j) {
        int gkv = ((const int*)&k4)[j];
        float va = ((const float*)&a0)[j];
        float vb = ((const float*)&a1)[j];
#pragma unroll
        for (int k = 0; k < 7; ++k) {
          bool m = (gkv == k + 1);
          float sel = m ? 1.f : 0.f;
          ka[k] += sel * va;
          kb2[k] += sel * vb;
          kcq[k] += m;
        }
      }
    }

#pragma unroll
    for (int k = 0; k < 7; ++k) {
      float fa = wredf(ka[k]);
      float fb = wredf(kb2[k]);
      if (lane == 0) { shSred[w * 14 + k] = fa; shSred[w * 14 + 7 + k] = fb; }
      if (lo) {
        unsigned rc = wredu(kcq[k]);
        if (lane == 0) shScnt[w * 7 + k] = rc;
      }
    }
    __syncthreads();
    if (tid < 14) {
      int k = tid % 7, c = tid / 7;      // c: 0 -> ch a, 1 -> ch b
      float s = shSred[c * 7 + k] + shSred[14 + c * 7 + k] +
                shSred[28 + c * 7 + k] + shSred[42 + c * 7 + k];
      if (s != 0.f)
        atomicAdd(&wsbf[OFF_KS + (k + 1) * 4 + (lo ? 0 : 2) + c], s);
    } else if (lo && tid >= 16 && tid < 23) {
      int k = tid - 16;
      unsigned s = shScnt[k] + shScnt[7 + k] + shScnt[14 + k] + shScnt[21 + k];
      if (s) atomicAdd(&wsb[OFF_KC + 1 + k], s);
    }
  }
}

// ---- kGB: role G (blocks 0..199) = agg loss (2 iters); role B'
//      (200..215) = select prologue + H0 scan + H1 hist ---------------------
__global__ __launch_bounds__(256) void kGB(const float* __restrict__ out_,
                                           const int* __restrict__ lab_,
                                           unsigned* __restrict__ ws) {
  const int b = blockIdx.y;
  unsigned* wsb = ws + (size_t)b * PER_BATCH;
  float* wsbf = (float*)wsb;
  const int tid = threadIdx.x, lane = tid & 63, w = tid >> 6;

  if (blockIdx.x < 200) {
    // ================= G role =================
    __shared__ float sG[32];
    __shared__ float sAgg[4 * 7];
    const int bx = blockIdx.x;
    if (tid < 32) {
      int inst = tid >> 2, c = tid & 3;
      float g = 0.f;
      if (inst >= 1) {
        unsigned kc = wsb[OFF_KC + inst];
        g = wsbf[OFF_KS + inst * 4 + c] / fmaxf((float)kc, 1.f);
      }
      sG[tid] = g;
    }
    __syncthreads();
    const int4* gt = (const int4*)(lab_ + (size_t)b * 2 * NPIX);
    const float4* s0 = (const float4*)(out_ + (size_t)b * 6 * NPIX + 2 * (size_t)NPIX);
    const float4* s1 = (const float4*)(out_ + (size_t)b * 6 * NPIX + 3 * (size_t)NPIX);
    const float4* s2 = (const float4*)(out_ + (size_t)b * 6 * NPIX + 4 * (size_t)NPIX);
    const float4* s3 = (const float4*)(out_ + (size_t)b * 6 * NPIX + 5 * (size_t)NPIX);
    float agg[7];
#pragma unroll
    for (int k = 0; k < 7; ++k) agg[k] = 0.f;
#pragma unroll
    for (int it = 0; it < 2; ++it) {
      const int i = it * 51200 + bx * 256 + tid;
      int4 g4 = gt[i];
      float4 a0 = s0[i], a1 = s1[i], a2 = s2[i], a3 = s3[i];
#pragma unroll
      for (int j = 0; j < 4; ++j) {
        int gtv = ((const int*)&g4)[j];
        bool pos = gtv > 0;
        int kk = pos ? gtv : 0;
        float d0 = ((const float*)&a0)[j] - sG[kk * 4 + 0];
        float d1 = ((const float*)&a1)[j] - sG[kk * 4 + 1];
        float d2 = ((const float*)&a2)[j] - sG[kk * 4 + 2];
        float d3 = ((const float*)&a3)[j] - sG[kk * 4 + 3];
        float sq = d0 * d0 + d1 * d1 + d2 * d2 + d3 * d3;
        float d = (sq > 0.f) ? sqrtf(sq) : 0.f;
        float dd = fmaxf(d - 0.5f, 0.f);
        float lg = pos ? __logf(1.f + dd * dd) : 0.f;
#pragma unroll
        for (int k = 0; k < 7; ++k) agg[k] += (gtv == k + 1) ? lg : 0.f;
      }
    }
#pragma unroll
    for (int k = 0; k < 7; ++k) {
      float f = wredf(agg[k]);
      if (lane == 0) sAgg[w * 7 + k] = f;
    }
    __syncthreads();
    if (tid < 7) {
      float s = sAgg[tid] + sAgg[7 + tid] + sAgg[14 + tid] + sAgg[21 + tid];
      if (s != 0.f) atomicAdd(&wsbf[OFF_AGG + 1 + tid], s);
    }
  } else {
    // ================= B' role =================
    const int bb = blockIdx.x - 200;   // 0..15
    __shared__ unsigned S[256];
    __shared__ unsigned sh_h1[2048];
    __shared__ unsigned sh_k, sh_pfx0;
    __shared__ int sh_fall;
    if (tid == 0) {
      unsigned cpos = wsb[OFF_CPOS], cposm = wsb[OFF_CPOSM];
      long posnum = (long)cpos - (long)cposm;
      long cneg = (long)NPIX - (long)cpos;
      long negnum = posnum * 3; if (negnum > cneg) negnum = cneg;
      int fall = (posnum == 0) || (negnum == 0);
      wsb[OFF_FALL] = (unsigned)fall;
      sh_fall = fall; sh_k = (unsigned)negnum;
      float G[8][4];
      unsigned nvv = 0, vm = 0;
      for (int k = 1; k < 8; ++k) {
        unsigned kc = wsb[OFF_KC + k], tc = wsb[OFF_TC + k];
        float inv = 1.f / fmaxf((float)kc, 1.f);
        for (int c = 0; c < 4; ++c) G[k][c] = wsbf[OFF_KS + k * 4 + c] * inv;
        if (kc > 0 && tc > 0) { vm |= 1u << k; ++nvv; }
      }
      wsb[OFF_NV] = nvv; wsb[OFF_VM] = vm;
      float s = 0.f;
      for (int i = 1; i < 8; ++i) {
        if (!((vm >> i) & 1)) continue;
        for (int j = i + 1; j < 8; ++j) {
          if (!((vm >> j) & 1)) continue;
          float sq = 0.f;
          for (int c = 0; c < 4; ++c) { float d = G[i][c] - G[j][c]; sq += d * d; }
          float gn = (sq > 0.f) ? sqrtf(sq) : 0.f;
          float dd = fmaxf(3.0f - gn, 0.f);
          s += log1pf(dd * dd);
        }
      }
      float denom = (float)(nvv * (nvv > 0 ? nvv - 1u : 0u));
      wsbf[OFF_LDIS] = (nvv > 1) ? (s / fmaxf(denom, 1.f)) : 0.f;
    }
    __syncthreads();
    if (sh_fall) return;
    unsigned myp = 0;
#pragma unroll
    for (int j = 0; j < 8; ++j) myp += wsb[OFF_H0 + tid * 8 + j];
    S[tid] = myp;
    __syncthreads();
#pragma unroll
    for (int off = 1; off < 256; off <<= 1) {
      unsigned v = (tid + off < 256) ? S[tid + off] : 0u;
      __syncthreads();
      S[tid] += v;
      __syncthreads();
    }
    {
      unsigned k = sh_k;
      unsigned suf = S[tid], sufn = suf - myp;
      if (suf >= k && sufn < k) {
        unsigned kk = k - sufn;
        unsigned cum2 = 0; int bin = tid * 8;
#pragma unroll
        for (int j = 7; j >= 0; --j) {
          unsigned h = wsb[OFF_H0 + tid * 8 + j]; cum2 += h;
          if (cum2 >= kk) { bin = tid * 8 + j; kk -= (cum2 - h); break; }
        }
        sh_pfx0 = (unsigned)bin;
        wsb[OFF_PFX0] = (unsigned)bin;   // dup same-value writes: benign
        wsb[OFF_K1] = kk;
      }
    }
    __syncthreads();
    const unsigned pfx = sh_pfx0;
    const unsigned kn = wsb[OFF_KN];
    for (int i = tid; i < 2048; i += 256) sh_h1[i] = 0u;
    __syncthreads();
    const unsigned* keys = ws + KEYS_BASE + (size_t)b * NPIX;
    for (unsigned i = bb * 256u + tid; i < kn; i += 16u * 256u) {
      unsigned key = keys[i];
      if ((key >> 21) == pfx) atomicAdd(&sh_h1[(key >> 10) & 0x7FFu], 1u);
    }
    __syncthreads();
    for (int i = tid; i < 2048; i += 256) {
      unsigned v = sh_h1[i]; if (v) atomicAdd(&wsb[OFF_H1 + i], v);
    }
  }
}

// ---- kCD: 16 blocks/batch. Redundant H1 scan -> pfx22,k2; then H2 hist -----
__global__ __launch_bounds__(256) void kCD(unsigned* __restrict__ ws) {
  const int b = blockIdx.y;
  unsigned* wsb = ws + (size_t)b * PER_BATCH;
  if (wsb[OFF_FALL]) return;
  __shared__ unsigned S[256];
  __shared__ unsigned sh_h2[1024];
  __shared__ unsigned sh_p22;
  const int tid = threadIdx.x;
  unsigned myp = 0;
#pragma unroll
  for (int j = 0; j < 8; ++j) myp += wsb[OFF_H1 + tid * 8 + j];
  S[tid] = myp;
  __syncthreads();
#pragma unroll
  for (int off = 1; off < 256; off <<= 1) {
    unsigned v = (tid + off < 256) ? S[tid + off] : 0u;
    __syncthreads();
    S[tid] += v;
    __syncthreads();
  }
  {
    unsigned k = wsb[OFF_K1];
    unsigned suf = S[tid], sufn = suf - myp;
    if (suf >= k && sufn < k) {
      unsigned kk = k - sufn;
      unsigned cum2 = 0; int bin = tid * 8;
#pragma unroll
      for (int j = 7; j >= 0; --j) {
        unsigned h = wsb[OFF_H1 + tid * 8 + j]; cum2 += h;
        if (cum2 >= kk) { bin = tid * 8 + j; kk -= (cum2 - h); break; }
      }
      unsigned p22 = (wsb[OFF_PFX0] << 11) | (unsigned)bin;
      sh_p22 = p22;
      wsb[OFF_PFX22] = p22;   // dup same-value writes: benign
      wsb[OFF_K2] = kk;
    }
  }
  __syncthreads();
  const unsigned pfx22 = sh_p22;
  const unsigned kn = wsb[OFF_KN];
  for (int i = tid; i < 1024; i += 256) sh_h2[i] = 0u;
  __syncthreads();
  const unsigned* keys = ws + KEYS_BASE + (size_t)b * NPIX;
  for (unsigned i = blockIdx.x * 256u + tid; i < kn; i += 16u * 256u) {
    unsigned key = keys[i];
    if ((key >> 10) == pfx22) atomicAdd(&sh_h2[key & 0x3FFu], 1u);
  }
  __syncthreads();
  for (int i = tid; i < 1024; i += 256) {
    unsigned v = sh_h2[i]; if (v) atomicAdd(&wsb[OFF_H2 + i], v);
  }
}

// ---- kEF: 16 blocks/batch. Redundant H2 scan -> thkey; then bt_neg ---------
__global__ __launch_bounds__(256) void kEF(unsigned* __restrict__ ws) {
  const int b = blockIdx.y;
  unsigned* wsb = ws + (size_t)b * PER_BATCH;
  float* wsbf = (float*)wsb;
  if (wsb[OFF_FALL]) return;
  __shared__ unsigned S[256];
  __shared__ unsigned sh_thk;
  __shared__ float sF[4];
  const int tid = threadIdx.x, lane = tid & 63, w = tid >> 6;
  unsigned myp = 0;
#pragma unroll
  for (int j = 0; j < 4; ++j) myp += wsb[OFF_H2 + tid * 4 + j];
  S[tid] = myp;
  __syncthreads();
#pragma unroll
  for (int off = 1; off < 256; off <<= 1) {
    unsigned v = (tid + off < 256) ? S[tid + off] : 0u;
    __syncthreads();
    S[tid] += v;
    __syncthreads();
  }
  {
    unsigned k = wsb[OFF_K2];
    unsigned suf = S[tid], sufn = suf - myp;
    if (suf >= k && sufn < k) {
      unsigned kk = k - sufn;
      unsigned cum2 = 0; int bin = tid * 4;
#pragma unroll
      for (int j = 3; j >= 0; --j) {
        unsigned h = wsb[OFF_H2 + tid * 4 + j]; cum2 += h;
        if (cum2 >= kk) { bin = tid * 4 + j; break; }
      }
      sh_thk = (wsb[OFF_PFX22] << 10) | (unsigned)bin;
    }
  }
  __syncthreads();
  const unsigned thkey = sh_thk;
  const unsigned knF = wsb[OFF_KNF];
  const unsigned* listB = ws + KEYS_BASE + (size_t)b * NPIX + (NPIX - knF);
  float part = 0.f;
  for (unsigned i = blockIdx.x * 256u + tid; i < knF; i += 16u * 256u) {
    unsigned key = listB[i];
    if (key >= thkey) {
      float sg = sigf(unmapf(key));
      part += sg * sg;
    }
  }
  part = wredf(part);
  if (lane == 0) sF[w] = part;
  __syncthreads();
  if (tid == 0) {
    float s = sF[0] + sF[1] + sF[2] + sF[3];
    if (s != 0.f) atomicAdd(&wsbf[OFF_BTN], s);
  }
}

// ---- kH: finalize 5 scalars -------------------------------------------------
__global__ void kH(const unsigned* __restrict__ ws, float* __restrict__ out) {
  __shared__ float sv[4][8];
  const int b = threadIdx.x;
  if (b < 8) {
    const unsigned* wsb = ws + (size_t)b * PER_BATCH;
    const float* wsbf = (const float*)wsb;
    int fall = (int)wsb[OFF_FALL];
    float at, bt, ct;
    if (fall) {
      at = wsbf[OFF_DICE + 3]; bt = wsbf[OFF_DICE + 4]; ct = wsbf[OFF_DICE + 5];
    } else {
      at = wsbf[OFF_DICE + 0];
      bt = wsbf[OFF_DICE + 1] + wsbf[OFF_BTN];
      ct = wsbf[OFF_DICE + 2];
    }
    float lt = 1.f - 2.f * at / ((bt + 1e-3f) + (ct + 1e-3f));
    float ak = wsbf[OFF_DICE + 6], bk = wsbf[OFF_DICE + 7] + 1e-3f, ck = wsbf[OFF_DICE + 8] + 1e-3f;
    float lk = 1.f - 2.f * ak / (bk + ck);
    unsigned vm = wsb[OFF_VM], nvv = wsb[OFF_NV];
    float s = 0.f;
    for (int k = 1; k < 8; ++k)
      if ((vm >> k) & 1) s += wsbf[OFF_AGG + k] / fmaxf((float)wsb[OFF_TC + k], 1.f);
    float la = s / fmaxf((float)nvv, 1.f);
    float ld = wsbf[OFF_LDIS];
    sv[0][b] = lt; sv[1][b] = lk; sv[2][b] = la; sv[3][b] = ld;
  }
  __syncthreads();
  if (threadIdx.x == 0) {
    float mt = 0.f, mk = 0.f, ma = 0.f, md = 0.f;
    for (int i = 0; i < 8; ++i) { mt += sv[0][i]; mk += sv[1][i]; ma += sv[2][i]; md += sv[3][i]; }
    mt *= 0.125f; mk *= 0.125f; ma *= 0.125f; md *= 0.125f;
    out[0] = mt + 0.5f * mk + 0.25f * (ma + md);
    out[1] = mt;
    out[2] = mk;
    out[3] = ma;
    out[4] = md;
  }
}

extern "C" void kernel_launch(void* const* d_in, const int* in_sizes, int n_in,
                              void* d_out, int out_size, void* d_ws, size_t ws_size,
                              hipStream_t stream) {
  const float* outputs = (const float*)d_in[0];
  const int* labels = (const int*)d_in[1];
  const float* tm = (const float*)d_in[2];
  unsigned* ws = (unsigned*)d_ws;
  float* out = (float*)d_out;

  dim3 blk(256);
  kZ<<<(HDR_WORDS + 255) / 256, blk, 0, stream>>>(ws);
  kXS<<<dim3(456, NB), blk, 0, stream>>>(outputs, labels, tm, ws);
  kGB<<<dim3(216, NB), blk, 0, stream>>>(outputs, labels, ws);
  kCD<<<dim3(16, NB), blk, 0, stream>>>(ws);
  kEF<<<dim3(16, NB), blk, 0, stream>>>(ws);
  kH<<<1, 64, 0, stream>>>(ws, out);
}

// Round 16
// 82.525 us; speedup vs baseline: 1.1072x; 1.1072x over previous
//
#include <hip/hip_runtime.h>

#define NPIX 409600   // 640*640
#define NB 8          // batch

// ---------------- workspace layout (4-byte words, per batch) ----------------
constexpr int OFF_H0   = 0;     // 2048 u32  level-0 hist (key bits 31..21)
constexpr int OFF_H1   = 2048;  // 2048 u32  level-1 hist (bits 20..10)
constexpr int OFF_H2   = 4096;  // 1024 u32  level-2 hist (bits 9..0)
constexpr int OFF_KC   = 5120;  // 8 u32   kernel-mask counts
constexpr int OFF_TC   = 5128;  // 8 u32   text-mask counts
constexpr int OFF_KS   = 5136;  // 32 f32  kernel-mask sim sums (inst*4+c)
constexpr int OFF_AGG  = 5168;  // 8 f32   per-instance sum log1p(D)
constexpr int OFF_CPOS = 5176;  // u32
constexpr int OFF_CPOSM= 5177;  // u32
constexpr int OFF_KN   = 5178;  // u32  list-A count (all negs)
constexpr int OFF_KNF  = 5179;  // u32  list-B count (flagged negs)
constexpr int OFF_FALL = 5180;  // u32
constexpr int OFF_NV   = 5181;  // u32
constexpr int OFF_VM   = 5182;  // u32
constexpr int OFF_LDIS = 5183;  // f32
constexpr int OFF_BTN  = 5184;  // f32  bt_neg (threshold-dependent dice part)
constexpr int OFF_PFX0 = 5185;  // u32
constexpr int OFF_K1   = 5186;  // u32
constexpr int OFF_PFX22= 5187;  // u32
constexpr int OFF_K2   = 5188;  // u32
constexpr int OFF_DICE = 5190;  // 9 f32: at,btp,ct, atf,btf,ctf, ak,bk,ck
constexpr int PER_BATCH= 5248;
constexpr int KEYS_BASE= NB * PER_BATCH;
constexpr int HDR_WORDS= NB * PER_BATCH;
// per-batch key region (NPIX words): list A grows up from 0,
// list B (flagged) grows down from NPIX-1.

__device__ __forceinline__ unsigned mapf(float s) {
  unsigned b = __float_as_uint(s);
  return (b & 0x80000000u) ? ~b : (b | 0x80000000u);
}
__device__ __forceinline__ float unmapf(unsigned u) {
  return __uint_as_float((u & 0x80000000u) ? (u & 0x7FFFFFFFu) : ~u);
}
__device__ __forceinline__ float sigf(float x) {
  return __fdividef(1.f, 1.f + __expf(-x));
}
__device__ __forceinline__ float wredf(float v) {
#pragma unroll
  for (int m = 32; m >= 1; m >>= 1) v += __shfl_xor(v, m, 64);
  return v;
}
__device__ __forceinline__ unsigned wredu(unsigned v) {
#pragma unroll
  for (int m = 32; m >= 1; m >>= 1) v += (unsigned)__shfl_xor((int)v, m, 64);
  return v;
}

// ---- kZ ---------------------------------------------------------------------
__global__ __launch_bounds__(256) void kZ(unsigned* __restrict__ ws) {
  int i = blockIdx.x * 256 + threadIdx.x;
  if (i < HDR_WORDS) ws[i] = 0u;
}

// ---- kXS: one launch, three block roles. ILP-deep loads (R15 lesson:
//      occupancy/stall fixes didn't move kXS; try 2x bytes-in-flight). ------
// role X  (blocks 0..99):   16 px/thread, 10 loads batched per half.
// role S01 (100..227): sim c0/c1 + KC, 2-deep strided loads, reg accum.
// role S23 (228..355): sim c2/c3, same.
__global__ __launch_bounds__(256) void kXS(const float* __restrict__ out_,
                                           const int* __restrict__ lab_,
                                           const float* __restrict__ tm_,
                                           unsigned* __restrict__ ws) {
  const int b = blockIdx.y;
  unsigned* wsb = ws + (size_t)b * PER_BATCH;
  float* wsbf = (float*)wsb;
  __shared__ __align__(16) unsigned shm[2384];
  const int tid = threadIdx.x, lane = tid & 63, w = tid >> 6;

  if (blockIdx.x < 100) {
    // ========================= role X =========================
    const int bx = blockIdx.x;
    unsigned* sh_h   = shm;                   // 2048
    unsigned* shScan = shm + 2048;            // 256
    unsigned* shTC   = shm + 2304;            // 28
    float*    shRed  = (float*)(shm + 2332);  // 36
    unsigned* shC    = shm + 2368;            // 8
    unsigned* shBase = shm + 2376;            // 2
    for (int i = tid; i < 2048; i += 256) sh_h[i] = 0u;
    __syncthreads();

    const float4* tx = (const float4*)(out_ + (size_t)b * 6 * NPIX);
    const float4* kr = (const float4*)(out_ + (size_t)b * 6 * NPIX + (size_t)NPIX);
    const int4* gt = (const int4*)(lab_ + (size_t)b * 2 * NPIX);
    const int4* gk = (const int4*)(lab_ + (size_t)b * 2 * NPIX + NPIX);
    const float4* tmv = (const float4*)(tm_ + (size_t)b * NPIX);

    unsigned cposm = 0, vmask = 0, fmask = 0;
    unsigned long long tnib = 0ull;           // 8-bit field per gtv value
    unsigned kreg[16];
    float at = 0.f, btp = 0.f, ct = 0.f, atf = 0.f, btf = 0.f, ctf = 0.f;
    float ak = 0.f, bk = 0.f, ck = 0.f;

    // 4 windows of 25600 float4; process as 2 groups of 2 windows,
    // 10 loads issued up-front per group (2x bytes in flight).
#pragma unroll
    for (int g = 0; g < 2; ++g) {
      const int i0 = (2 * g) * 25600 + bx * 256 + tid;
      const int i1 = (2 * g + 1) * 25600 + bx * 256 + tid;
      float4 t4a = tx[i0], q4a = kr[i0], m4a = tmv[i0];
      int4 g4a = gt[i0], k4a = gk[i0];
      float4 t4b = tx[i1], q4b = kr[i1], m4b = tmv[i1];
      int4 g4b = gt[i1], k4b = gk[i1];
#pragma unroll
      for (int h = 0; h < 2; ++h) {
        const float4& t4 = h ? t4b : t4a;
        const float4& q4 = h ? q4b : q4a;
        const float4& m4 = h ? m4b : m4a;
        const int4& g4 = h ? g4b : g4a;
        const int4& k4 = h ? k4b : k4a;
#pragma unroll
        for (int j = 0; j < 4; ++j) {
          float tv = ((const float*)&t4)[j];
          float kv = ((const float*)&q4)[j];
          int gtv = ((const int*)&g4)[j];
          int gkv = ((const int*)&k4)[j];
          float mv = ((const float*)&m4)[j];
          bool pos = gtv > 0;
          bool mh = mv > 0.5f;
          cposm += (pos && !mh);
          tnib += 1ull << ((unsigned)(gtv & 7) << 3);
          unsigned key = mapf(tv);
          int slot = g * 8 + h * 4 + j;
          kreg[slot] = key;
          float sig = sigf(tv);
          if (!pos) {
            vmask |= 1u << slot;
            if (mh) fmask |= 1u << slot;
            atomicAdd(&sh_h[key >> 21], 1u);
          } else if (mh) {
            at += sig; btp += sig * sig; ct += 1.f;
          }
          float sm = sig * mv;           // fallback dice (sel = tm float)
          btf += sm * sm;
          if (pos) { atf += sm * mv; ctf += mv * mv; }
          if ((tv > 0.f) && mh) {        // kernel dice
            float sk = sigf(kv);
            bk += sk * sk;
            if (gkv > 0) { ak += sk; ck += 1.f; }
          }
        }
      }
    }

    unsigned cpos = 16u - (unsigned)(tnib & 0xFFull);
    unsigned r = wredu(cpos), r2 = wredu(cposm);
    if (lane == 0) { shC[w * 2] = r; shC[w * 2 + 1] = r2; }
#pragma unroll
    for (int k = 0; k < 7; ++k) {
      unsigned rt = wredu((unsigned)((tnib >> ((k + 1) * 8)) & 0xFFull));
      if (lane == 0) shTC[w * 7 + k] = rt;
    }
    float v9[9] = {at, btp, ct, atf, btf, ctf, ak, bk, ck};
#pragma unroll
    for (int q = 0; q < 9; ++q) {
      float f = wredf(v9[q]);
      if (lane == 0) shRed[w * 9 + q] = f;
    }

    unsigned cnt = (unsigned)__popc(vmask), cntF = (unsigned)__popc(fmask);
    shScan[tid] = cnt | (cntF << 16);
    __syncthreads();
#pragma unroll
    for (int off = 1; off < 256; off <<= 1) {
      unsigned vv = (tid >= off) ? shScan[tid - off] : 0u;
      __syncthreads();
      shScan[tid] += vv;
      __syncthreads();
    }
    if (tid == 0) {
      unsigned tot = shScan[255];
      shBase[0] = atomicAdd(&wsb[OFF_KN], tot & 0xFFFFu);
      shBase[1] = atomicAdd(&wsb[OFF_KNF], tot >> 16);
    }
    for (int i = tid; i < 2048; i += 256) {
      unsigned h = sh_h[i]; if (h) atomicAdd(&wsb[OFF_H0 + i], h);
    }
    if (tid < 7) {
      unsigned s = shTC[tid] + shTC[7 + tid] + shTC[14 + tid] + shTC[21 + tid];
      if (s) atomicAdd(&wsb[OFF_TC + 1 + tid], s);
    } else if (tid >= 16 && tid < 25) {
      int q = tid - 16;
      float s = shRed[q] + shRed[9 + q] + shRed[18 + q] + shRed[27 + q];
      atomicAdd(&wsbf[OFF_DICE + q], s);
    } else if (tid == 30) {
      atomicAdd(&wsb[OFF_CPOS], shC[0] + shC[2] + shC[4] + shC[6]);
    } else if (tid == 31) {
      atomicAdd(&wsb[OFF_CPOSM], shC[1] + shC[3] + shC[5] + shC[7]);
    }
    __syncthreads();
    unsigned gA = shBase[0] + (shScan[tid] & 0xFFFFu) - cnt;
    unsigned gF = shBase[1] + (shScan[tid] >> 16) - cntF;
    unsigned* keys = ws + KEYS_BASE + (size_t)b * NPIX;
#pragma unroll
    for (int s = 0; s < 16; ++s)
      if (vmask & (1u << s)) { keys[gA] = kreg[s]; ++gA; }
#pragma unroll
    for (int s = 0; s < 16; ++s)
      if (fmask & (1u << s)) { keys[NPIX - 1 - gF] = kreg[s]; ++gF; }
  } else {
    // ==================== roles S01 / S23 (reg accum, 2-deep loads) =========
    const bool lo = blockIdx.x < 228;    // channels {0,1} : {2,3}
    const int bx = lo ? (blockIdx.x - 100) : (blockIdx.x - 228);
    float* shSred = (float*)shm;         // [4 waves][14]
    unsigned* shScnt = shm + 64;         // [4 waves][7]

    const float4* sa = (const float4*)(out_ + (size_t)b * 6 * NPIX + (size_t)(lo ? 2 : 4) * NPIX);
    const float4* sb = (const float4*)(out_ + (size_t)b * 6 * NPIX + (size_t)(lo ? 3 : 5) * NPIX);
    const int4* gkk = (const int4*)(lab_ + (size_t)b * 2 * NPIX + NPIX);

    float ka[7], kb2[7];
    unsigned long long knib = 0ull;
#pragma unroll
    for (int k = 0; k < 7; ++k) { ka[k] = 0.f; kb2[k] = 0.f; }

    const int nv = NPIX / 4;
    const int stride = 128 * 256;
    for (int i0 = bx * 256 + tid; i0 < nv; i0 += 2 * stride) {
      const int i1 = i0 + stride;
      const bool has1 = i1 < nv;
      int4 k4a = gkk[i0];
      float4 a0a = sa[i0], a1a = sb[i0];
      int4 k4b; float4 a0b, a1b;
      if (has1) { k4b = gkk[i1]; a0b = sa[i1]; a1b = sb[i1]; }
#pragma unroll
      for (int j = 0; j < 4; ++j) {
        int gkv = ((const int*)&k4a)[j];
        float va = ((const float*)&a0a)[j];
        float vb = ((const float*)&a1a)[j];
        knib += 1ull << ((unsigned)(gkv & 7) << 3);
#pragma unroll
        for (int k = 0; k < 7; ++k) {
          float sel = (gkv == k + 1) ? 1.f : 0.f;
          ka[k] += sel * va;
          kb2[k] += sel * vb;
        }
      }
      if (has1) {
#pragma unroll
        for (int j = 0; j < 4; ++j) {
          int gkv = ((const int*)&k4b)[j];
          float va = ((const float*)&a0b)[j];
          float vb = ((const float*)&a1b)[j];
          knib += 1ull << ((unsigned)(gkv & 7) << 3);
#pragma unroll
          for (int k = 0; k < 7; ++k) {
            float sel = (gkv == k + 1) ? 1.f : 0.f;
            ka[k] += sel * va;
            kb2[k] += sel * vb;
          }
        }
      }
    }

#pragma unroll
    for (int k = 0; k < 7; ++k) {
      float fa = wredf(ka[k]);
      float fb = wredf(kb2[k]);
      if (lane == 0) { shSred[w * 14 + k] = fa; shSred[w * 14 + 7 + k] = fb; }
      if (lo) {
        unsigned rc = wredu((unsigned)((knib >> ((k + 1) * 8)) & 0xFFull));
        if (lane == 0) shScnt[w * 7 + k] = rc;
      }
    }
    __syncthreads();
    if (tid < 14) {
      int k = tid % 7, c = tid / 7;      // c: 0 -> ch a, 1 -> ch b
      float s = shSred[c * 7 + k] + shSred[14 + c * 7 + k] +
                shSred[28 + c * 7 + k] + shSred[42 + c * 7 + k];
      if (s != 0.f)
        atomicAdd(&wsbf[OFF_KS + (k + 1) * 4 + (lo ? 0 : 2) + c], s);
    } else if (lo && tid >= 16 && tid < 23) {
      int k = tid - 16;
      unsigned s = shScnt[k] + shScnt[7 + k] + shScnt[14 + k] + shScnt[21 + k];
      if (s) atomicAdd(&wsb[OFF_KC + 1 + k], s);
    }
  }
}

// ---- kGB: role G (blocks 0..199) = agg loss (10 loads upfront); role B'
//      (200..215) = select prologue + H0 scan + H1 hist ---------------------
__global__ __launch_bounds__(256) void kGB(const float* __restrict__ out_,
                                           const int* __restrict__ lab_,
                                           unsigned* __restrict__ ws) {
  const int b = blockIdx.y;
  unsigned* wsb = ws + (size_t)b * PER_BATCH;
  float* wsbf = (float*)wsb;
  const int tid = threadIdx.x, lane = tid & 63, w = tid >> 6;

  if (blockIdx.x < 200) {
    // ================= G role =================
    __shared__ float sG[32];
    __shared__ float sAgg[4 * 7];
    const int bx = blockIdx.x;
    if (tid < 32) {
      int inst = tid >> 2, c = tid & 3;
      float g = 0.f;
      if (inst >= 1) {
        unsigned kc = wsb[OFF_KC + inst];
        g = wsbf[OFF_KS + inst * 4 + c] / fmaxf((float)kc, 1.f);
      }
      sG[tid] = g;
    }
    __syncthreads();
    const int4* gt = (const int4*)(lab_ + (size_t)b * 2 * NPIX);
    const float4* s0 = (const float4*)(out_ + (size_t)b * 6 * NPIX + 2 * (size_t)NPIX);
    const float4* s1 = (const float4*)(out_ + (size_t)b * 6 * NPIX + 3 * (size_t)NPIX);
    const float4* s2 = (const float4*)(out_ + (size_t)b * 6 * NPIX + 4 * (size_t)NPIX);
    const float4* s3 = (const float4*)(out_ + (size_t)b * 6 * NPIX + 5 * (size_t)NPIX);
    float agg[7];
#pragma unroll
    for (int k = 0; k < 7; ++k) agg[k] = 0.f;
    const int i0 = bx * 256 + tid;
    const int i1 = 51200 + bx * 256 + tid;
    int4 g4a = gt[i0];
    float4 a0a = s0[i0], a1a = s1[i0], a2a = s2[i0], a3a = s3[i0];
    int4 g4b = gt[i1];
    float4 a0b = s0[i1], a1b = s1[i1], a2b = s2[i1], a3b = s3[i1];
#pragma unroll
    for (int h = 0; h < 2; ++h) {
      const int4& g4 = h ? g4b : g4a;
      const float4& a0 = h ? a0b : a0a;
      const float4& a1 = h ? a1b : a1a;
      const float4& a2 = h ? a2b : a2a;
      const float4& a3 = h ? a3b : a3a;
#pragma unroll
      for (int j = 0; j < 4; ++j) {
        int gtv = ((const int*)&g4)[j];
        bool pos = gtv > 0;
        int kk = pos ? gtv : 0;
        float d0 = ((const float*)&a0)[j] - sG[kk * 4 + 0];
        float d1 = ((const float*)&a1)[j] - sG[kk * 4 + 1];
        float d2 = ((const float*)&a2)[j] - sG[kk * 4 + 2];
        float d3 = ((const float*)&a3)[j] - sG[kk * 4 + 3];
        float sq = d0 * d0 + d1 * d1 + d2 * d2 + d3 * d3;
        float d = (sq > 0.f) ? sqrtf(sq) : 0.f;
        float dd = fmaxf(d - 0.5f, 0.f);
        float lg = pos ? __logf(1.f + dd * dd) : 0.f;
#pragma unroll
        for (int k = 0; k < 7; ++k) agg[k] += (gtv == k + 1) ? lg : 0.f;
      }
    }
#pragma unroll
    for (int k = 0; k < 7; ++k) {
      float f = wredf(agg[k]);
      if (lane == 0) sAgg[w * 7 + k] = f;
    }
    __syncthreads();
    if (tid < 7) {
      float s = sAgg[tid] + sAgg[7 + tid] + sAgg[14 + tid] + sAgg[21 + tid];
      if (s != 0.f) atomicAdd(&wsbf[OFF_AGG + 1 + tid], s);
    }
  } else {
    // ================= B' role =================
    const int bb = blockIdx.x - 200;   // 0..15
    __shared__ unsigned S[256];
    __shared__ unsigned sh_h1[2048];
    __shared__ unsigned sh_k, sh_pfx0;
    __shared__ int sh_fall;
    if (tid == 0) {
      unsigned cpos = wsb[OFF_CPOS], cposm = wsb[OFF_CPOSM];
      long posnum = (long)cpos - (long)cposm;
      long cneg = (long)NPIX - (long)cpos;
      long negnum = posnum * 3; if (negnum > cneg) negnum = cneg;
      int fall = (posnum == 0) || (negnum == 0);
      wsb[OFF_FALL] = (unsigned)fall;
      sh_fall = fall; sh_k = (unsigned)negnum;
      float G[8][4];
      unsigned nvv = 0, vm = 0;
      for (int k = 1; k < 8; ++k) {
        unsigned kc = wsb[OFF_KC + k], tc = wsb[OFF_TC + k];
        float inv = 1.f / fmaxf((float)kc, 1.f);
        for (int c = 0; c < 4; ++c) G[k][c] = wsbf[OFF_KS + k * 4 + c] * inv;
        if (kc > 0 && tc > 0) { vm |= 1u << k; ++nvv; }
      }
      wsb[OFF_NV] = nvv; wsb[OFF_VM] = vm;
      float s = 0.f;
      for (int i = 1; i < 8; ++i) {
        if (!((vm >> i) & 1)) continue;
        for (int j = i + 1; j < 8; ++j) {
          if (!((vm >> j) & 1)) continue;
          float sq = 0.f;
          for (int c = 0; c < 4; ++c) { float d = G[i][c] - G[j][c]; sq += d * d; }
          float gn = (sq > 0.f) ? sqrtf(sq) : 0.f;
          float dd = fmaxf(3.0f - gn, 0.f);
          s += log1pf(dd * dd);
        }
      }
      float denom = (float)(nvv * (nvv > 0 ? nvv - 1u : 0u));
      wsbf[OFF_LDIS] = (nvv > 1) ? (s / fmaxf(denom, 1.f)) : 0.f;
    }
    __syncthreads();
    if (sh_fall) return;
    unsigned myp = 0;
#pragma unroll
    for (int j = 0; j < 8; ++j) myp += wsb[OFF_H0 + tid * 8 + j];
    S[tid] = myp;
    __syncthreads();
#pragma unroll
    for (int off = 1; off < 256; off <<= 1) {
      unsigned v = (tid + off < 256) ? S[tid + off] : 0u;
      __syncthreads();
      S[tid] += v;
      __syncthreads();
    }
    {
      unsigned k = sh_k;
      unsigned suf = S[tid], sufn = suf - myp;
      if (suf >= k && sufn < k) {
        unsigned kk = k - sufn;
        unsigned cum2 = 0; int bin = tid * 8;
#pragma unroll
        for (int j = 7; j >= 0; --j) {
          unsigned h = wsb[OFF_H0 + tid * 8 + j]; cum2 += h;
          if (cum2 >= kk) { bin = tid * 8 + j; kk -= (cum2 - h); break; }
        }
        sh_pfx0 = (unsigned)bin;
        wsb[OFF_PFX0] = (unsigned)bin;   // dup same-value writes: benign
        wsb[OFF_K1] = kk;
      }
    }
    __syncthreads();
    const unsigned pfx = sh_pfx0;
    const unsigned kn = wsb[OFF_KN];
    for (int i = tid; i < 2048; i += 256) sh_h1[i] = 0u;
    __syncthreads();
    const unsigned* keys = ws + KEYS_BASE + (size_t)b * NPIX;
    for (unsigned i = bb * 256u + tid; i < kn; i += 16u * 256u) {
      unsigned key = keys[i];
      if ((key >> 21) == pfx) atomicAdd(&sh_h1[(key >> 10) & 0x7FFu], 1u);
    }
    __syncthreads();
    for (int i = tid; i < 2048; i += 256) {
      unsigned v = sh_h1[i]; if (v) atomicAdd(&wsb[OFF_H1 + i], v);
    }
  }
}

// ---- kCD: 16 blocks/batch. Redundant H1 scan -> pfx22,k2; then H2 hist -----
__global__ __launch_bounds__(256) void kCD(unsigned* __restrict__ ws) {
  const int b = blockIdx.y;
  unsigned* wsb = ws + (size_t)b * PER_BATCH;
  if (wsb[OFF_FALL]) return;
  __shared__ unsigned S[256];
  __shared__ unsigned sh_h2[1024];
  __shared__ unsigned sh_p22;
  const int tid = threadIdx.x;
  unsigned myp = 0;
#pragma unroll
  for (int j = 0; j < 8; ++j) myp += wsb[OFF_H1 + tid * 8 + j];
  S[tid] = myp;
  __syncthreads();
#pragma unroll
  for (int off = 1; off < 256; off <<= 1) {
    unsigned v = (tid + off < 256) ? S[tid + off] : 0u;
    __syncthreads();
    S[tid] += v;
    __syncthreads();
  }
  {
    unsigned k = wsb[OFF_K1];
    unsigned suf = S[tid], sufn = suf - myp;
    if (suf >= k && sufn < k) {
      unsigned kk = k - sufn;
      unsigned cum2 = 0; int bin = tid * 8;
#pragma unroll
      for (int j = 7; j >= 0; --j) {
        unsigned h = wsb[OFF_H1 + tid * 8 + j]; cum2 += h;
        if (cum2 >= kk) { bin = tid * 8 + j; kk -= (cum2 - h); break; }
      }
      unsigned p22 = (wsb[OFF_PFX0] << 11) | (unsigned)bin;
      sh_p22 = p22;
      wsb[OFF_PFX22] = p22;   // dup same-value writes: benign
      wsb[OFF_K2] = kk;
    }
  }
  __syncthreads();
  const unsigned pfx22 = sh_p22;
  const unsigned kn = wsb[OFF_KN];
  for (int i = tid; i < 1024; i += 256) sh_h2[i] = 0u;
  __syncthreads();
  const unsigned* keys = ws + KEYS_BASE + (size_t)b * NPIX;
  for (unsigned i = blockIdx.x * 256u + tid; i < kn; i += 16u * 256u) {
    unsigned key = keys[i];
    if ((key >> 10) == pfx22) atomicAdd(&sh_h2[key & 0x3FFu], 1u);
  }
  __syncthreads();
  for (int i = tid; i < 1024; i += 256) {
    unsigned v = sh_h2[i]; if (v) atomicAdd(&wsb[OFF_H2 + i], v);
  }
}

// ---- kEF: 16 blocks/batch. Redundant H2 scan -> thkey; then bt_neg ---------
__global__ __launch_bounds__(256) void kEF(unsigned* __restrict__ ws) {
  const int b = blockIdx.y;
  unsigned* wsb = ws + (size_t)b * PER_BATCH;
  float* wsbf = (float*)wsb;
  if (wsb[OFF_FALL]) return;
  __shared__ unsigned S[256];
  __shared__ unsigned sh_thk;
  __shared__ float sF[4];
  const int tid = threadIdx.x, lane = tid & 63, w = tid >> 6;
  unsigned myp = 0;
#pragma unroll
  for (int j = 0; j < 4; ++j) myp += wsb[OFF_H2 + tid * 4 + j];
  S[tid] = myp;
  __syncthreads();
#pragma unroll
  for (int off = 1; off < 256; off <<= 1) {
    unsigned v = (tid + off < 256) ? S[tid + off] : 0u;
    __syncthreads();
    S[tid] += v;
    __syncthreads();
  }
  {
    unsigned k = wsb[OFF_K2];
    unsigned suf = S[tid], sufn = suf - myp;
    if (suf >= k && sufn < k) {
      unsigned kk = k - sufn;
      unsigned cum2 = 0; int bin = tid * 4;
#pragma unroll
      for (int j = 3; j >= 0; --j) {
        unsigned h = wsb[OFF_H2 + tid * 4 + j]; cum2 += h;
        if (cum2 >= kk) { bin = tid * 4 + j; break; }
      }
      sh_thk = (wsb[OFF_PFX22] << 10) | (unsigned)bin;
    }
  }
  __syncthreads();
  const unsigned thkey = sh_thk;
  const unsigned knF = wsb[OFF_KNF];
  const unsigned* listB = ws + KEYS_BASE + (size_t)b * NPIX + (NPIX - knF);
  float part = 0.f;
  for (unsigned i = blockIdx.x * 256u + tid; i < knF; i += 16u * 256u) {
    unsigned key = listB[i];
    if (key >= thkey) {
      float sg = sigf(unmapf(key));
      part += sg * sg;
    }
  }
  part = wredf(part);
  if (lane == 0) sF[w] = part;
  __syncthreads();
  if (tid == 0) {
    float s = sF[0] + sF[1] + sF[2] + sF[3];
    if (s != 0.f) atomicAdd(&wsbf[OFF_BTN], s);
  }
}

// ---- kH: finalize 5 scalars -------------------------------------------------
__global__ void kH(const unsigned* __restrict__ ws, float* __restrict__ out) {
  __shared__ float sv[4][8];
  const int b = threadIdx.x;
  if (b < 8) {
    const unsigned* wsb = ws + (size_t)b * PER_BATCH;
    const float* wsbf = (const float*)wsb;
    int fall = (int)wsb[OFF_FALL];
    float at, bt, ct;
    if (fall) {
      at = wsbf[OFF_DICE + 3]; bt = wsbf[OFF_DICE + 4]; ct = wsbf[OFF_DICE + 5];
    } else {
      at = wsbf[OFF_DICE + 0];
      bt = wsbf[OFF_DICE + 1] + wsbf[OFF_BTN];
      ct = wsbf[OFF_DICE + 2];
    }
    float lt = 1.f - 2.f * at / ((bt + 1e-3f) + (ct + 1e-3f));
    float ak = wsbf[OFF_DICE + 6], bk = wsbf[OFF_DICE + 7] + 1e-3f, ck = wsbf[OFF_DICE + 8] + 1e-3f;
    float lk = 1.f - 2.f * ak / (bk + ck);
    unsigned vm = wsb[OFF_VM], nvv = wsb[OFF_NV];
    float s = 0.f;
    for (int k = 1; k < 8; ++k)
      if ((vm >> k) & 1) s += wsbf[OFF_AGG + k] / fmaxf((float)wsb[OFF_TC + k], 1.f);
    float la = s / fmaxf((float)nvv, 1.f);
    float ld = wsbf[OFF_LDIS];
    sv[0][b] = lt; sv[1][b] = lk; sv[2][b] = la; sv[3][b] = ld;
  }
  __syncthreads();
  if (threadIdx.x == 0) {
    float mt = 0.f, mk = 0.f, ma = 0.f, md = 0.f;
    for (int i = 0; i < 8; ++i) { mt += sv[0][i]; mk += sv[1][i]; ma += sv[2][i]; md += sv[3][i]; }
    mt *= 0.125f; mk *= 0.125f; ma *= 0.125f; md *= 0.125f;
    out[0] = mt + 0.5f * mk + 0.25f * (ma + md);
    out[1] = mt;
    out[2] = mk;
    out[3] = ma;
    out[4] = md;
  }
}

extern "C" void kernel_launch(void* const* d_in, const int* in_sizes, int n_in,
                              void* d_out, int out_size, void* d_ws, size_t ws_size,
                              hipStream_t stream) {
  const float* outputs = (const float*)d_in[0];
  const int* labels = (const int*)d_in[1];
  const float* tm = (const float*)d_in[2];
  unsigned* ws = (unsigned*)d_ws;
  float* out = (float*)d_out;

  dim3 blk(256);
  kZ<<<(HDR_WORDS + 255) / 256, blk, 0, stream>>>(ws);
  kXS<<<dim3(356, NB), blk, 0, stream>>>(outputs, labels, tm, ws);
  kGB<<<dim3(216, NB), blk, 0, stream>>>(outputs, labels, ws);
  kCD<<<dim3(16, NB), blk, 0, stream>>>(ws);
  kEF<<<dim3(16, NB), blk, 0, stream>>>(ws);
  kH<<<1, 64, 0, stream>>>(ws, out);
}